// Round 7
// baseline (416.901 us; speedup 1.0000x reference)
//
#include <hip/hip_runtime.h>
#include <hip/hip_bf16.h>

typedef __bf16 bf16x8 __attribute__((ext_vector_type(8)));
typedef __bf16 bf16x4 __attribute__((ext_vector_type(4)));
typedef float  f32x4  __attribute__((ext_vector_type(4)));

#define T_TOK    8192
#define D_DIM    1024
#define H_DIM    2048
#define E_NUM    8
#define MAX_MB   136      // 17*8 (128-row blocks)
#define MAX_ROWS 17408    // 136*128

// ---- workspace layout (bytes) ----
#define OFF_MBTOT   512
#define OFF_MB2E    1024
#define OFF_MBROW0  2048
#define OFF_TOPKE   4096            // 16384 ints  -> ends 69632
#define OFF_TOPKS   69632           // 16384 float -> ends 135168
#define OFF_TOK     135168          // 17408 ints  -> ends 204800
#define OFF_ROWIDX  204800          // 16384 ints  -> ends 270336
#define OFF_XB      (1u<<20)                    // 8192*1024*2  = 16 MiB
#define OFF_W1T     (18u*1024*1024)             // 8*2048*1024*2 = 32 MiB -> ends 50 MiB
#define OFF_W2T     (50u*1024*1024)             // 8*1024*2048*2 = 32 MiB -> ends 82 MiB
#define OFF_HBUF    (82u*1024*1024)             // 17408*2048*2  = 68 MiB -> ends 150 MiB
#define OFF_YBUF    OFF_XB                      // ybuf overlaid on xb+W1T (dead after gemm1)

__device__ __forceinline__ void gload_lds16(const void* g, void* l) {
    __builtin_amdgcn_global_load_lds(
        (const __attribute__((address_space(1))) void*)g,
        (__attribute__((address_space(3))) void*)l, 16, 0, 0);
}

// ---------------- fused router (+ fp32->bf16 convert of x), NO atomics ----------------
__global__ __launch_bounds__(256) void k_router_cvt(
    const float* __restrict__ x, const float* __restrict__ Wg,
    __bf16* __restrict__ xb, int* __restrict__ topk_e, float* __restrict__ topk_s)
{
    __shared__ float wgT[E_NUM][1032];   // padded stride
    const int tid = threadIdx.x;
#pragma unroll
    for (int i = 0; i < 32; ++i) {
        int f = tid + i * 256;           // coalesced read of Wg[1024][8]
        wgT[f & 7][f >> 3] = Wg[f];
    }
    __syncthreads();

    const int wave = tid >> 6, lane = tid & 63;
    const int t = blockIdx.x * 4 + wave;
    const float* xr = x + (size_t)t * D_DIM;
    __bf16* xbr = xb + (size_t)t * D_DIM;

    float acc[E_NUM];
#pragma unroll
    for (int e = 0; e < E_NUM; ++e) acc[e] = 0.f;

#pragma unroll
    for (int j = 0; j < 4; ++j) {
        const int d0 = lane * 4 + j * 256;
        float4 xv = *(const float4*)(xr + d0);
        bf16x4 o = { (__bf16)xv.x, (__bf16)xv.y, (__bf16)xv.z, (__bf16)xv.w };
        *(bf16x4*)(xbr + d0) = o;
#pragma unroll
        for (int e = 0; e < E_NUM; ++e) {
            float4 wv = *(const float4*)&wgT[e][d0];
            acc[e] += xv.x * wv.x + xv.y * wv.y + xv.z * wv.z + xv.w * wv.w;
        }
    }
#pragma unroll
    for (int off = 32; off >= 1; off >>= 1)
#pragma unroll
        for (int e = 0; e < E_NUM; ++e) acc[e] += __shfl_xor(acc[e], off, 64);

    if (lane == 0) {
        int e0 = 0; float v0 = acc[0];
#pragma unroll
        for (int e = 1; e < E_NUM; ++e) if (acc[e] > v0) { v0 = acc[e]; e0 = e; }
        int e1 = -1; float v1 = -1e30f;
#pragma unroll
        for (int e = 0; e < E_NUM; ++e) if (e != e0 && acc[e] > v1) { v1 = acc[e]; e1 = e; }
        float s0 = 1.f / (1.f + __expf(v1 - v0));  // renormalized top-2 softmax
        float s1 = 1.f - s0;
        topk_e[t*2+0] = e0; topk_e[t*2+1] = e1;
        topk_s[t*2+0] = s0; topk_s[t*2+1] = s1;
    }
}

// ---------------- single-block counting sort (round-0 proven version) ----------------
#define SORT_T 256
__global__ __launch_bounds__(512) void k_sort(
    const int* __restrict__ topk_e,
    int* __restrict__ mbTot, int* __restrict__ mb2e, int* __restrict__ mbrow0,
    int* __restrict__ tok, int* __restrict__ rowidx)
{
    __shared__ int lcnt[E_NUM][SORT_T];
    __shared__ int base[E_NUM];
    __shared__ int etot[E_NUM];
    const int tid = threadIdx.x;

    if (tid < SORT_T) {
#pragma unroll
        for (int e = 0; e < E_NUM; ++e) lcnt[e][tid] = 0;
    }
    __syncthreads();

    if (tid < SORT_T) {
        const int4* p = (const int4*)(topk_e + tid * 64);
#pragma unroll
        for (int i = 0; i < 16; ++i) {
            int4 v = p[i];
            lcnt[v.x][tid]++; lcnt[v.y][tid]++; lcnt[v.z][tid]++; lcnt[v.w][tid]++;
        }
    }
    __syncthreads();

    {
        const int w = tid >> 6, l = tid & 63;
        int v0 = lcnt[w][l*4+0], v1 = lcnt[w][l*4+1], v2 = lcnt[w][l*4+2], v3 = lcnt[w][l*4+3];
        int s = v0 + v1 + v2 + v3;
        int inc = s;
#pragma unroll
        for (int off = 1; off < 64; off <<= 1) {
            int o = __shfl_up(inc, off, 64);
            if (l >= off) inc += o;
        }
        int exc = inc - s;
        lcnt[w][l*4+0] = exc;
        lcnt[w][l*4+1] = exc + v0;
        lcnt[w][l*4+2] = exc + v0 + v1;
        lcnt[w][l*4+3] = exc + v0 + v1 + v2;
        if (l == 63) etot[w] = inc;
    }
    __syncthreads();

    if (tid == 0) {
        int row = 0, mb = 0;
        for (int e = 0; e < E_NUM; ++e) {
            base[e] = row;
            int nb = (etot[e] + 127) >> 7;
            for (int b = 0; b < nb; ++b) { mb2e[mb] = e; mbrow0[mb] = row + b*128; ++mb; }
            row += nb * 128;
        }
        mbTot[0] = mb;
    }
    __syncthreads();

    if (tid < SORT_T) {
#pragma unroll
        for (int e = 0; e < E_NUM; ++e) lcnt[e][tid] += base[e];
        const int4* p = (const int4*)(topk_e + tid * 64);
#pragma unroll
        for (int i = 0; i < 16; ++i) {
            int4 v = p[i];
            int j0 = tid * 64 + i * 4;
            int r;
            r = lcnt[v.x][tid]++; tok[r] = (j0+0) >> 1; rowidx[j0+0] = r;
            r = lcnt[v.y][tid]++; tok[r] = (j0+1) >> 1; rowidx[j0+1] = r;
            r = lcnt[v.z][tid]++; tok[r] = (j0+2) >> 1; rowidx[j0+2] = r;
            r = lcnt[v.w][tid]++; tok[r] = (j0+3) >> 1; rowidx[j0+3] = r;
        }
    }
}

// ---------------- transpose+convert: in [E][R][C] f32 -> out [E][C][R] bf16 ----------------
__global__ __launch_bounds__(256) void k_transpose(
    const float* __restrict__ in, __bf16* __restrict__ out, int R, int C)
{
    __shared__ float tile[64][65];
    const int e = blockIdx.z;
    const float* inp = in + (size_t)e * R * C;
    __bf16* outp = out + (size_t)e * R * C;
    const int r0 = blockIdx.x * 64, c0 = blockIdx.y * 64;
    const int c = threadIdx.x & 63, rr = threadIdx.x >> 6;
#pragma unroll
    for (int i = 0; i < 16; ++i) {
        int r = rr + i * 4;
        tile[r][c] = inp[(size_t)(r0 + r) * C + c0 + c];
    }
    __syncthreads();
#pragma unroll
    for (int i = 0; i < 16; ++i) {
        int cc = rr + i * 4;
        outp[(size_t)(c0 + cc) * R + r0 + c] = (__bf16)tile[c][cc];
    }
}

// ====== 128x256 / BK=32 grouped GEMM, asymmetric-depth pipeline (R7) ======
// 512 thr = 8 waves (2M x 4N); wave tile 64x64; acc[4][4] f32x4.
// LDS 80 KiB: A[4 slots][128][32]bf16 (32K) @0 + B[3 slots][256][32] (48K)
// @32768 -> 2 blocks/CU (2*81920 = 160 KiB exactly).
// Swizzle (r0-proven, 0 conflicts): global src chunk cg=(tid&3)^((tid>>3)&3),
// LDS dest linear, read chunk qx=(q^((r>>1)&3))*16.
// PIPELINE (the round-7 change): A staged 3 tiles ahead (first-touch HBM,
// ~900cy), B staged 2 ahead (L2-resident, ~250cy). Per iter t: read A[t&3],
// B[t%3]; issue B(t+2) then A(t+3); drain vmcnt(4) retires exactly
// {A(t+1), B(t+1)x2} -> A lead ~2 iters (~1400cy > HBM), B lead ~1 iter.
// Round-6's symmetric vmcnt(3) gave A only ~1 iter lead -> per-iter HBM stall.

#define LDSB_OFF 32768

#define BARR __builtin_amdgcn_s_barrier()
#define WVM4 asm volatile("s_waitcnt vmcnt(4)" ::: "memory")
#define WVM3 asm volatile("s_waitcnt vmcnt(3)" ::: "memory")
#define WVM0 asm volatile("s_waitcnt vmcnt(0)" ::: "memory")
#define P1 __builtin_amdgcn_s_setprio(1)
#define P0 __builtin_amdgcn_s_setprio(0)

// stage tile T_'s A into A-slot SL_ (1 gload/thread)
#define STAGE_A(SL_, T_) { \
    gload_lds16(pA + (T_)*32, smem + (SL_)*8192 + wq); }
// stage tile T_'s B into B-slot SL_ (2 gloads/thread)
#define STAGE_B(SL_, T_) { \
    gload_lds16(pB0 + (T_)*32, smem + LDSB_OFF + (SL_)*16384 + wq); \
    gload_lds16(pB1 + (T_)*32, smem + LDSB_OFF + (SL_)*16384 + 8192 + wq); }

#define RD_TILE(ASL_, BSL_) { \
    const char* ba = smem + (ASL_)*8192; \
    const char* bb = smem + LDSB_OFF + (BSL_)*16384; \
    av[0] = *(const bf16x8*)(ba + (wm*64 +  0 + r)*64 + qx); \
    av[1] = *(const bf16x8*)(ba + (wm*64 + 16 + r)*64 + qx); \
    av[2] = *(const bf16x8*)(ba + (wm*64 + 32 + r)*64 + qx); \
    av[3] = *(const bf16x8*)(ba + (wm*64 + 48 + r)*64 + qx); \
    bv[0] = *(const bf16x8*)(bb + (wn*64 +  0 + r)*64 + qx); \
    bv[1] = *(const bf16x8*)(bb + (wn*64 + 16 + r)*64 + qx); \
    bv[2] = *(const bf16x8*)(bb + (wn*64 + 32 + r)*64 + qx); \
    bv[3] = *(const bf16x8*)(bb + (wn*64 + 48 + r)*64 + qx); }

#define MFMA16 { \
    _Pragma("unroll") \
    for (int mi = 0; mi < 4; ++mi) \
    _Pragma("unroll") \
    for (int ni = 0; ni < 4; ++ni) \
        acc[mi][ni] = __builtin_amdgcn_mfma_f32_16x16x32_bf16(av[mi], bv[ni], acc[mi][ni], 0, 0, 0); }

template<int KD, int NBLK, bool GATHER, bool RELU>
__global__ __launch_bounds__(512, 4) void k_gemm(
    const __bf16* __restrict__ Asrc, const __bf16* __restrict__ WT,
    const float* __restrict__ bias, const int* __restrict__ tok,
    const int* __restrict__ mb2e, const int* __restrict__ mbrow0,
    const int* __restrict__ mbTot, __bf16* __restrict__ outp)
{
    constexpr int NT = KD / 32;          // 32 (gemm1) or 64 (gemm2); >= 5
    constexpr int NOUT = NBLK * 256;
    __shared__ __align__(16) char smem[81920];

    const int id   = blockIdx.x;
    const int xcd  = id & 7;
    const int j    = id >> 3;
    const int nblk = j % NBLK;
    const int mbi  = (j / NBLK) * 8 + xcd;
    if (mbi >= *mbTot) return;
    const int e    = mb2e[mbi];
    const int row0 = mbrow0[mbi];
    const int n0   = nblk * 256;

    const int tid = threadIdx.x;
    const int w = tid >> 6, l = tid & 63;
    const int r = l & 15, q = l >> 4;
    const int wm = w >> 2, wn = w & 3;       // 2M x 4N wave grid
    const int wq = w * 1024;                  // wave-uniform LDS stage base
    const int qx = (q ^ ((r >> 1) & 3)) * 16; // swizzled read chunk (r0-proven)

    // ---- staging source pointers: pre-swizzled global chunk (involution) ----
    const int cg = (tid & 3) ^ ((tid >> 3) & 3);  // row = tid>>2 -> (row>>1)&3 = (tid>>3)&3
    const __bf16* Wb = WT + (size_t)e * ((size_t)NOUT * KD);
    const __bf16* pA;
    {
        int ar = row0 + (tid >> 2);           // 128 rows, 4 chunks each
        pA = GATHER ? Asrc + (size_t)tok[ar] * KD + cg * 8
                    : Asrc + (size_t)ar * KD + cg * 8;
    }
    const __bf16* pB0 = Wb + (size_t)(n0 + (tid >> 2)) * KD + cg * 8;
    const __bf16* pB1 = Wb + (size_t)(n0 + 128 + (tid >> 2)) * KD + cg * 8;

    f32x4 acc[4][4];
#pragma unroll
    for (int mi = 0; mi < 4; ++mi)
#pragma unroll
        for (int ni = 0; ni < 4; ++ni) acc[mi][ni] = (f32x4){0.f, 0.f, 0.f, 0.f};

    bf16x8 av[4], bv[4];

    // ---- prologue: FIFO = [B0,B0,A0, A1,B1,B1,A2]; drain first 3 (B0,A0) ----
    STAGE_B(0, 0); STAGE_A(0, 0);
    STAGE_A(1, 1); STAGE_B(1, 1);
    STAGE_A(2, 2);
    WVM4; BARR;

    // ---- main loop: iter t reads A[t&3],B[t%3]; stages B(t+2), A(t+3) ----
    int rb = 0;                               // B read slot = t % 3
    for (int t = 0; t < NT - 3; ++t) {
        RD_TILE(t & 3, rb);
        int sb = (rb == 0) ? 2 : rb - 1;      // (t+2) % 3
        STAGE_B(sb, t + 2);                   // B first, then A (FIFO order!)
        STAGE_A((t + 3) & 3, t + 3);
        P1; MFMA16; P0;
        WVM4;                                  // retires A(t+1), B(t+1)x2
        BARR;
        rb = (rb == 2) ? 0 : rb + 1;
    }
    // t = NT-3: stage last B(NT-1); drain {A(NT-2), B(NT-2)x2}
    RD_TILE((NT - 3) & 3, rb);
    {
        int sb = (rb == 0) ? 2 : rb - 1;
        STAGE_B(sb, NT - 1);
    }
    P1; MFMA16; P0;
    WVM3; BARR;
    rb = (rb == 2) ? 0 : rb + 1;
    // t = NT-2: drain remaining {A(NT-1), B(NT-1)x2}
    RD_TILE((NT - 2) & 3, rb);
    P1; MFMA16; P0;
    WVM0; BARR;
    rb = (rb == 2) ? 0 : rb + 1;
    // t = NT-1
    RD_TILE((NT - 1) & 3, rb);
    P1; MFMA16; P0;

    // ---- epilogue: bias (+relu); pad rows land in pad region (harmless) ----
    const float* be = bias + (size_t)e * NOUT;
    float bb4[4];
#pragma unroll
    for (int ni = 0; ni < 4; ++ni) bb4[ni] = be[n0 + wn*64 + ni*16 + r];
#pragma unroll
    for (int mi = 0; mi < 4; ++mi)
#pragma unroll
        for (int reg = 0; reg < 4; ++reg) {
            int row = row0 + wm*64 + mi*16 + q*4 + reg;
            __bf16* orow = outp + (size_t)row * NOUT + n0 + wn*64;
#pragma unroll
            for (int ni = 0; ni < 4; ++ni) {
                float v = acc[mi][ni][reg] + bb4[ni];
                if (RELU) v = fmaxf(v, 0.f);
                orow[ni*16 + r] = (__bf16)v;
            }
        }
}

// ---------------- combine: out[t] = s0*y[r0] + s1*y[r1] ----------------
__global__ __launch_bounds__(256) void k_combine(
    const __bf16* __restrict__ ybuf, const int* __restrict__ rowidx,
    const float* __restrict__ topk_s, float* __restrict__ out)
{
    const int t = blockIdx.x;
    const int d0 = threadIdx.x * 4;
    const int r0 = rowidx[t*2+0], r1 = rowidx[t*2+1];
    const float s0 = topk_s[t*2+0], s1 = topk_s[t*2+1];
    bf16x4 y0 = *(const bf16x4*)(ybuf + (size_t)r0 * D_DIM + d0);
    bf16x4 y1 = *(const bf16x4*)(ybuf + (size_t)r1 * D_DIM + d0);
    float4 o;
    o.x = s0 * (float)y0[0] + s1 * (float)y1[0];
    o.y = s0 * (float)y0[1] + s1 * (float)y1[1];
    o.z = s0 * (float)y0[2] + s1 * (float)y1[2];
    o.w = s0 * (float)y0[3] + s1 * (float)y1[3];
    *(float4*)(out + (size_t)t * D_DIM + d0) = o;
}

extern "C" void kernel_launch(void* const* d_in, const int* in_sizes, int n_in,
                              void* d_out, int out_size, void* d_ws, size_t ws_size,
                              hipStream_t stream) {
    const float* x  = (const float*)d_in[0];
    const float* Wg = (const float*)d_in[1];
    const float* W1 = (const float*)d_in[2];
    const float* b1 = (const float*)d_in[3];
    const float* W2 = (const float*)d_in[4];
    const float* b2 = (const float*)d_in[5];
    float* out = (float*)d_out;
    char* ws = (char*)d_ws;

    int*   mbTot  = (int*)  (ws + OFF_MBTOT);
    int*   mb2e   = (int*)  (ws + OFF_MB2E);
    int*   mbrow0 = (int*)  (ws + OFF_MBROW0);
    int*   topk_e = (int*)  (ws + OFF_TOPKE);
    float* topk_s = (float*)(ws + OFF_TOPKS);
    int*   tok    = (int*)  (ws + OFF_TOK);
    int*   rowidx = (int*)  (ws + OFF_ROWIDX);
    __bf16* xb   = (__bf16*)(ws + OFF_XB);
    __bf16* W1T  = (__bf16*)(ws + OFF_W1T);
    __bf16* W2T  = (__bf16*)(ws + OFF_W2T);
    __bf16* hbuf = (__bf16*)(ws + OFF_HBUF);
    __bf16* ybuf = (__bf16*)(ws + OFF_YBUF);

    // zero tok (pad rows -> tok=0). tables fully written by k_sort.
    hipMemsetAsync(ws + OFF_TOK, 0, MAX_ROWS * sizeof(int), stream);

    k_router_cvt<<<T_TOK/4, 256, 0, stream>>>(x, Wg, xb, topk_e, topk_s);
    k_sort      <<<1, 512, 0, stream>>>(topk_e, mbTot, mb2e, mbrow0, tok, rowidx);
    k_transpose <<<dim3(D_DIM/64, H_DIM/64, E_NUM), 256, 0, stream>>>(W1, W1T, D_DIM, H_DIM);
    k_transpose <<<dim3(H_DIM/64, D_DIM/64, E_NUM), 256, 0, stream>>>(W2, W2T, H_DIM, D_DIM);

    k_gemm<D_DIM, 8, true,  true ><<<MAX_MB * 8, 512, 0, stream>>>(
        xb, W1T, b1, tok, mb2e, mbrow0, mbTot, hbuf);
    k_gemm<H_DIM, 4, false, false><<<MAX_MB * 4, 512, 0, stream>>>(
        hbuf, W2T, b2, tok, mb2e, mbrow0, mbTot, ybuf);

    k_combine<<<T_TOK, 256, 0, stream>>>(ybuf, rowidx, topk_s, out);
}